// Round 9
// baseline (445.222 us; speedup 1.0000x reference)
//
#include <hip/hip_runtime.h>
#include <hip/hip_fp16.h>
#include <math.h>

typedef _Float16 f16x8 __attribute__((ext_vector_type(8)));
typedef float f32x4 __attribute__((ext_vector_type(4)));

// ---------------- graph preprocessing ----------------

// counting pass; atomicAdd's return value IS the edge's rank within its dst bucket
__global__ void k_edge_count(const int* __restrict__ dst, int* __restrict__ ecnt,
                             int* __restrict__ rank, int E) {
    int j = (blockIdx.x * 256 + threadIdx.x) * 2;
    if (j + 1 < E) {
        int2 d = *(const int2*)(dst + j);
        int r0 = atomicAdd(&ecnt[d.x], 1);
        int r1 = atomicAdd(&ecnt[d.y], 1);
        *(int2*)(rank + j) = make_int2(r0, r1);
    } else if (j < E) {
        rank[j] = atomicAdd(&ecnt[dst[j]], 1);
    }
}

__global__ void k_scanA(const int* __restrict__ ecnt, int* __restrict__ bsum, int N) {
    int t = threadIdx.x;
    int base = blockIdx.x * 1024;
    int s = 0;
#pragma unroll
    for (int j = 0; j < 4; ++j) {
        int i = base + j * 256 + t;
        if (i < N) s += ecnt[i];
    }
#pragma unroll
    for (int off = 32; off > 0; off >>= 1) s += __shfl_down(s, off, 64);
    __shared__ int wsum[4];
    if ((t & 63) == 0) wsum[t >> 6] = s;
    __syncthreads();
    if (t == 0) bsum[blockIdx.x] = wsum[0] + wsum[1] + wsum[2] + wsum[3];
}

__global__ void k_scanB(const int* __restrict__ bsum, int* __restrict__ boff, int NB,
                        int* __restrict__ rowstart, int N, int E) {
    __shared__ int sh[256];
    int t = threadIdx.x;
    int v = (t < NB) ? bsum[t] : 0;
    sh[t] = v;
    __syncthreads();
    for (int off = 1; off < 256; off <<= 1) {
        int u = (t >= off) ? sh[t - off] : 0;
        __syncthreads();
        sh[t] += u;
        __syncthreads();
    }
    if (t < NB) boff[t] = sh[t] - v;  // exclusive
    if (t == 0) rowstart[N] = E;
}

__global__ void k_scanC(const int* __restrict__ ecnt, const int* __restrict__ boff,
                        int* __restrict__ rowstart, float* __restrict__ dinv, int N) {
    int t = threadIdx.x;
    int base = blockIdx.x * 1024 + t * 4;
    int e[4];
    int s = 0;
#pragma unroll
    for (int j = 0; j < 4; ++j) {
        int i = base + j;
        e[j] = (i < N) ? ecnt[i] : 0;
        s += e[j];
    }
    __shared__ int sh[256];
    sh[t] = s;
    __syncthreads();
    for (int off = 1; off < 256; off <<= 1) {
        int u = (t >= off) ? sh[t - off] : 0;
        __syncthreads();
        sh[t] += u;
        __syncthreads();
    }
    int off0 = boff[blockIdx.x] + sh[t] - s;
    int run = 0;
#pragma unroll
    for (int j = 0; j < 4; ++j) {
        int i = base + j;
        if (i < N) {
            rowstart[i] = off0 + run;
            dinv[i] = rsqrtf((float)(e[j] + 1));  // +1 self loop
        }
        run += e[j];
    }
}

// atomic-free scatter: slot = rowstart[dst] + rank (4 edges/thread, full MLP)
__global__ void k_scatter(const int* __restrict__ src, const int* __restrict__ dst,
                          const int* __restrict__ rowstart, const int* __restrict__ rank,
                          int* __restrict__ ssrc, int E) {
    int j = (blockIdx.x * 256 + threadIdx.x) * 4;
    if (j + 3 < E) {
        int4 s = *(const int4*)(src + j);
        int4 d = *(const int4*)(dst + j);
        int4 r = *(const int4*)(rank + j);
        ssrc[rowstart[d.x] + r.x] = s.x;
        ssrc[rowstart[d.y] + r.y] = s.y;
        ssrc[rowstart[d.z] + r.z] = s.z;
        ssrc[rowstart[d.w] + r.w] = s.w;
    } else {
        for (; j < E; ++j) ssrc[rowstart[dst[j]] + rank[j]] = src[j];
    }
}

// ---------------- fused prologue: ecnt init + gstarts + x cast + W transpose ----------------
// all tasks independent; grid covers the largest (the cast, N*32 threads)

__global__ __launch_bounds__(256) void k_misc(
    const float* __restrict__ x, __half* __restrict__ xh,
    const float* __restrict__ W1, const float* __restrict__ W2,
    _Float16* __restrict__ W1t, _Float16* __restrict__ W2t,
    const int* __restrict__ batch, int* __restrict__ gstart,
    int* __restrict__ ecnt, int N, int G, int n4) {
    int i = blockIdx.x * 256 + threadIdx.x;
    if (i < n4) {  // f32 -> f16 cast, 4 elems/thread
        float4 v = *(const float4*)(x + (size_t)i * 4);
        union { __half2 h[2]; float2 f; } u;
        u.h[0] = __floats2half2_rn(v.x, v.y);
        u.h[1] = __floats2half2_rn(v.z, v.w);
        *(float2*)(xh + (size_t)i * 4) = u.f;
    }
    if (i < N) {
        ecnt[i] = 0;
        int bi = batch[i];
        int bp = (i == 0) ? -1 : batch[i - 1];
        for (int g = bp + 1; g <= bi; ++g) gstart[g] = i;
        if (i == N - 1) {
            for (int g = bi + 1; g <= G; ++g) gstart[g] = N;
        }
    }
    if (i < 128 * 256) {
        int c = i >> 7, k = i & 127;
        W1t[i] = (_Float16)W1[k * 256 + c];
    } else if (i < 128 * 256 + 256 * 256) {
        int j = i - 128 * 256;
        int c = j >> 8, k = j & 255;
        W2t[j] = (_Float16)W2[k * 256 + c];
    }
}

// ---------------- fused layer-1: aggregate(x) -> LDS -> MFMA GEMM -> h1h ----------------
// Per 64-row chunk: 16 quarter-waves gather 16 nodes/round x 4 rounds into the
// SWIZZLED LDS layout (write XOR (row&7)<<4 == read XOR (l&7)<<4 since row&7==l&7),
// then the standard B-in-registers MFMA phase computes relu(xa @ W1 + b1).

__global__ __launch_bounds__(256, 2) void k_agg_gemm1(
    const _Float16* __restrict__ xh, const int* __restrict__ rowstart,
    const int* __restrict__ ssrc, const float* __restrict__ dinv,
    const float* __restrict__ bias, const _Float16* __restrict__ Wt,
    _Float16* __restrict__ Ch, int Nrows, int nchunks) {
    constexpr int K = 128, KS = K / 32, RB = 2 * K;
    __shared__ _Float16 As[64 * K];

    int tid = threadIdx.x;
    int l = tid & 63;
    int wv = tid >> 6;
    int qw = tid >> 4, l16 = tid & 15;

    // ---- B prologue: 4 col-tiles x KS k-steps, registers
    int bc = wv * 64 + (l & 15);
    int bk = (l >> 4) * 8;
    f16x8 breg[4][KS];
#pragma unroll
    for (int ct = 0; ct < 4; ++ct)
#pragma unroll
        for (int ks = 0; ks < KS; ++ks)
            breg[ct][ks] = *(const f16x8*)(Wt + (size_t)(bc + ct * 16) * K + ks * 32 + bk);
    float bb[4];
#pragma unroll
    for (int ct = 0; ct < 4; ++ct) bb[ct] = bias[bc + ct * 16];

    for (int ch = blockIdx.x; ch < nchunks; ch += gridDim.x) {
        int r0 = ch * 64;
        // ---- gather phase: 4 rounds x 16 quarter-waves = 64 rows
#pragma unroll
        for (int round = 0; round < 4; ++round) {
            int row = round * 16 + qw;
            int v = r0 + row;
            float acc[8] = {0.f, 0.f, 0.f, 0.f, 0.f, 0.f, 0.f, 0.f};
            if (v < Nrows) {
                float dv = dinv[v];
                f16x8 s = *(const f16x8*)(xh + (size_t)v * 128 + l16 * 8);
#pragma unroll
                for (int j = 0; j < 8; ++j) acc[j] = (float)s[j] * dv;
                int e = rowstart[v], e1 = rowstart[v + 1];
                for (; e + 4 <= e1; e += 4) {
                    int u0 = ssrc[e], u1 = ssrc[e + 1], u2 = ssrc[e + 2], u3 = ssrc[e + 3];
                    float d0 = dinv[u0], d1 = dinv[u1], d2 = dinv[u2], d3 = dinv[u3];
                    f16x8 m0 = *(const f16x8*)(xh + (size_t)u0 * 128 + l16 * 8);
                    f16x8 m1 = *(const f16x8*)(xh + (size_t)u1 * 128 + l16 * 8);
                    f16x8 m2 = *(const f16x8*)(xh + (size_t)u2 * 128 + l16 * 8);
                    f16x8 m3 = *(const f16x8*)(xh + (size_t)u3 * 128 + l16 * 8);
#pragma unroll
                    for (int j = 0; j < 8; ++j) {
                        acc[j] = fmaf((float)m0[j], d0, acc[j]);
                        acc[j] = fmaf((float)m1[j], d1, acc[j]);
                        acc[j] = fmaf((float)m2[j], d2, acc[j]);
                        acc[j] = fmaf((float)m3[j], d3, acc[j]);
                    }
                }
                for (; e < e1; ++e) {
                    int u = ssrc[e];
                    float d = dinv[u];
                    f16x8 m = *(const f16x8*)(xh + (size_t)u * 128 + l16 * 8);
#pragma unroll
                    for (int j = 0; j < 8; ++j) acc[j] = fmaf((float)m[j], d, acc[j]);
                }
#pragma unroll
                for (int j = 0; j < 8; ++j) acc[j] *= dv;
            }
            f16x8 o;
#pragma unroll
            for (int j = 0; j < 8; ++j) o[j] = (_Float16)acc[j];
            int lb = row * RB + ((l16 * 16) ^ ((row & 7) << 4));
            *(f16x8*)((char*)As + lb) = o;
        }
        __syncthreads();

        // ---- MFMA phase: 4 row-blocks x KS x 4 col-tiles
#pragma unroll
        for (int rb = 0; rb < 4; ++rb) {
            f32x4 acc[4];
#pragma unroll
            for (int ct = 0; ct < 4; ++ct) acc[ct] = (f32x4){0.f, 0.f, 0.f, 0.f};
            int row = rb * 16 + (l & 15);
#pragma unroll
            for (int ks = 0; ks < KS; ++ks) {
                int lb = (row * RB + ks * 64 + (l >> 4) * 16) ^ ((l & 7) << 4);
                f16x8 a = *(const f16x8*)((const char*)As + lb);
#pragma unroll
                for (int ct = 0; ct < 4; ++ct)
                    acc[ct] = __builtin_amdgcn_mfma_f32_16x16x32_f16(a, breg[ct][ks], acc[ct], 0, 0, 0);
            }
            int rbase = r0 + rb * 16 + (l >> 4) * 4;
#pragma unroll
            for (int j = 0; j < 4; ++j) {
                int r = rbase + j;
                if (r < Nrows) {
#pragma unroll
                    for (int ct = 0; ct < 4; ++ct)
                        Ch[(size_t)r * 256 + bc + ct * 16] =
                            (_Float16)fmaxf(acc[ct][j] + bb[ct], 0.f);
                }
            }
        }
        __syncthreads();
    }
}

// ---------------- layer-2 MFMA GEMM (unchanged, EPI0: dinv scale, fp16 out) ----------------

template<int K, int EPI>
__global__ __launch_bounds__(256, 2) void k_gemm_mfma(
    const _Float16* __restrict__ Ah, const _Float16* __restrict__ Wt,
    const float* __restrict__ dinv, const float* __restrict__ bias,
    _Float16* __restrict__ Ch, int Nrows, int nchunks) {
    constexpr int KS = K / 32;
    constexpr int RB = 2 * K;
    constexpr int NLD = 64 * RB / 4096;
    __shared__ _Float16 As[64 * K];

    int tid = threadIdx.x;
    int l = tid & 63;
    int wv = tid >> 6;

    int bc = wv * 64 + (l & 15);
    int bk = (l >> 4) * 8;
    f16x8 breg[4][KS];
#pragma unroll
    for (int ct = 0; ct < 4; ++ct)
#pragma unroll
        for (int ks = 0; ks < KS; ++ks)
            breg[ct][ks] = *(const f16x8*)(Wt + (size_t)(bc + ct * 16) * K + ks * 32 + bk);
    float bb[4];
    if (EPI == 1) {
#pragma unroll
        for (int ct = 0; ct < 4; ++ct) bb[ct] = bias[bc + ct * 16];
    }

    for (int ch = blockIdx.x; ch < nchunks; ch += gridDim.x) {
        int r0 = ch * 64;
#pragma unroll
        for (int i = 0; i < NLD; ++i) {
            int logical = i * 4096 + tid * 16;
            int row = logical / RB;
            int colb = (logical & (RB - 1)) ^ ((row & 7) << 4);
            int grow = r0 + row;
            grow = grow < Nrows ? grow : Nrows - 1;
            const char* src = (const char*)Ah + (size_t)grow * RB + colb;
            char* dst = (char*)As + i * 4096 + wv * 1024;
            __builtin_amdgcn_global_load_lds(
                (const __attribute__((address_space(1))) void*)src,
                (__attribute__((address_space(3))) void*)dst, 16, 0, 0);
        }
        __syncthreads();

#pragma unroll
        for (int rb = 0; rb < 4; ++rb) {
            f32x4 acc[4];
#pragma unroll
            for (int ct = 0; ct < 4; ++ct) acc[ct] = (f32x4){0.f, 0.f, 0.f, 0.f};
            int row = rb * 16 + (l & 15);
#pragma unroll
            for (int ks = 0; ks < KS; ++ks) {
                int lb = (row * RB + ks * 64 + (l >> 4) * 16) ^ ((l & 7) << 4);
                f16x8 a = *(const f16x8*)((const char*)As + lb);
#pragma unroll
                for (int ct = 0; ct < 4; ++ct)
                    acc[ct] = __builtin_amdgcn_mfma_f32_16x16x32_f16(a, breg[ct][ks], acc[ct], 0, 0, 0);
            }
            int rbase = r0 + rb * 16 + (l >> 4) * 4;
#pragma unroll
            for (int j = 0; j < 4; ++j) {
                int r = rbase + j;
                if (r < Nrows) {
                    if (EPI == 0) {
                        float sc = dinv[r];
#pragma unroll
                        for (int ct = 0; ct < 4; ++ct)
                            Ch[(size_t)r * 256 + bc + ct * 16] = (_Float16)(acc[ct][j] * sc);
                    } else {
#pragma unroll
                        for (int ct = 0; ct < 4; ++ct)
                            Ch[(size_t)r * 256 + bc + ct * 16] =
                                (_Float16)fmaxf(acc[ct][j] + bb[ct], 0.f);
                    }
                }
            }
        }
        __syncthreads();
    }
}

// ---------------- layer-2 aggregation (proven shape, fp16 in AND out) ----------------

__device__ __forceinline__ void acc_h4s(float4& acc, float2 raw) {
    union { float2 f; __half2 h[2]; } u;
    u.f = raw;
    float2 p0 = __half22float2(u.h[0]);
    float2 p1 = __half22float2(u.h[1]);
    acc.x += p0.x; acc.y += p0.y; acc.z += p1.x; acc.w += p1.y;
}

__global__ __launch_bounds__(256) void k_aggregate(
    const __half* __restrict__ hsh, const int* __restrict__ rowstart,
    const int* __restrict__ ssrc, const float* __restrict__ dinv,
    const float* __restrict__ bias, __half* __restrict__ h2h, int N) {
    int w = threadIdx.x >> 6;
    int l = threadIdx.x & 63;
    int v = blockIdx.x * 4 + w;
    if (v >= N) return;
    float4 acc = make_float4(0.f, 0.f, 0.f, 0.f);
    acc_h4s(acc, *(const float2*)(hsh + (size_t)v * 256 + l * 4));  // self loop
    int e = rowstart[v], e1 = rowstart[v + 1];
    for (; e + 4 <= e1; e += 4) {
        int u0 = ssrc[e], u1 = ssrc[e + 1], u2 = ssrc[e + 2], u3 = ssrc[e + 3];
        float2 m0 = *(const float2*)(hsh + (size_t)u0 * 256 + l * 4);
        float2 m1 = *(const float2*)(hsh + (size_t)u1 * 256 + l * 4);
        float2 m2 = *(const float2*)(hsh + (size_t)u2 * 256 + l * 4);
        float2 m3 = *(const float2*)(hsh + (size_t)u3 * 256 + l * 4);
        acc_h4s(acc, m0);
        acc_h4s(acc, m1);
        acc_h4s(acc, m2);
        acc_h4s(acc, m3);
    }
    for (; e < e1; ++e) {
        int u = ssrc[e];
        acc_h4s(acc, *(const float2*)(hsh + (size_t)u * 256 + l * 4));
    }
    float d = dinv[v];
    float4 b = *(const float4*)(bias + l * 4);
    union { __half2 h[2]; float2 f; } uo;
    uo.h[0] = __floats2half2_rn(fmaxf(fmaf(acc.x, d, b.x), 0.f),
                                fmaxf(fmaf(acc.y, d, b.y), 0.f));
    uo.h[1] = __floats2half2_rn(fmaxf(fmaf(acc.z, d, b.z), 0.f),
                                fmaxf(fmaf(acc.w, d, b.w), 0.f));
    *(float2*)(h2h + (size_t)v * 256 + l * 4) = uo.f;
}

// ---------------- fused pool + head ----------------

__global__ __launch_bounds__(256) void k_poolhead(
    const __half* __restrict__ h2h, const int* __restrict__ gstart,
    const float* __restrict__ Wl, const float* __restrict__ bl,
    float* __restrict__ out, int G) {
    int g = blockIdx.x;
    int t = threadIdx.x;
    int i0 = gstart[g], i1 = gstart[g + 1];
    float s = 0.f;
    for (int i = i0; i < i1; ++i) s += __half2float(h2h[(size_t)i * 256 + t]);
    float pooled = s / fmaxf((float)(i1 - i0), 1.f);
    float v = pooled * Wl[t];
#pragma unroll
    for (int off = 32; off > 0; off >>= 1) v += __shfl_down(v, off, 64);
    __shared__ float red[4];
    if ((t & 63) == 0) red[t >> 6] = v;
    __syncthreads();
    if (t == 0) out[g] = red[0] + red[1] + red[2] + red[3] + bl[0];
}

// ---------------- launch ----------------

extern "C" void kernel_launch(void* const* d_in, const int* in_sizes, int n_in,
                              void* d_out, int out_size, void* d_ws, size_t ws_size,
                              hipStream_t stream) {
    const float* x  = (const float*)d_in[0];
    const int* ei   = (const int*)d_in[1];
    const int* batch= (const int*)d_in[2];
    const float* W1 = (const float*)d_in[3];
    const float* b1 = (const float*)d_in[4];
    const float* W2 = (const float*)d_in[5];
    const float* b2 = (const float*)d_in[6];
    const float* Wl = (const float*)d_in[7];
    const float* bl = (const float*)d_in[8];
    float* out = (float*)d_out;

    const int N = in_sizes[2];
    const int E = in_sizes[1] / 2;
    const int G = out_size;

    char* wsp = (char*)d_ws;
    size_t off = 0;
    auto carve = [&](size_t bytes) -> void* {
        void* p = wsp + off;
        off = (off + bytes + 255) & ~(size_t)255;
        return p;
    };
    float* bufA    = (float*)carve((size_t)N * 256 * 4);
    float* bufB    = (float*)carve((size_t)N * 256 * 4);
    float* dinv    = (float*)carve((size_t)N * 4);
    int* ecnt      = (int*)carve((size_t)N * 4);
    int* rowstart  = (int*)carve((size_t)(N + 1) * 4);
    int* rank      = (int*)carve((size_t)E * 4);
    int* ssrc      = (int*)carve((size_t)E * 4);
    const int NB = (N + 1023) / 1024;
    int* bsum      = (int*)carve((size_t)NB * 4);
    int* boff      = (int*)carve((size_t)NB * 4);
    int* gstart    = (int*)carve((size_t)(G + 1) * 4);
    _Float16* W1t  = (_Float16*)carve((size_t)256 * 128 * 2);
    _Float16* W2t  = (_Float16*)carve((size_t)256 * 256 * 2);
    (void)ws_size;

    // aliases (liveness-checked, sequential stream):
    // bufA: xh [0,25.6MB) | (unused 25.6MB) | h1h [51.2,102.4)
    // bufB: hsh [0,51.2)  | h2h [51.2,102.4)
    _Float16* xh   = (_Float16*)bufA;
    _Float16* h1h  = (_Float16*)((char*)bufA + (size_t)N * 128 * 4);
    _Float16* hsh  = (_Float16*)bufB;
    __half*   h2h  = (__half*)((char*)bufB + (size_t)N * 256 * 2);

    const int* esrc = ei;
    const int* edst = ei + E;

    int nchunks = (N + 63) / 64;
    int n4 = N * 32;  // float4 count for the cast

    hipLaunchKernelGGL(k_misc, dim3((n4 + 255) / 256), dim3(256), 0, stream,
                       x, (__half*)xh, W1, W2, W1t, W2t, batch, gstart, ecnt, N, G, n4);
    hipLaunchKernelGGL(k_edge_count, dim3((E / 2 + 255) / 256), dim3(256), 0, stream,
                       edst, ecnt, rank, E);
    hipLaunchKernelGGL(k_scanA, dim3(NB), dim3(256), 0, stream, ecnt, bsum, N);
    hipLaunchKernelGGL(k_scanB, dim3(1), dim3(256), 0, stream, bsum, boff, NB, rowstart, N, E);
    hipLaunchKernelGGL(k_scanC, dim3(NB), dim3(256), 0, stream, ecnt, boff, rowstart, dinv, N);
    hipLaunchKernelGGL(k_scatter, dim3((E / 4 + 255) / 256), dim3(256), 0, stream,
                       esrc, edst, rowstart, rank, ssrc, E);

    // layer 1 (fused): h1h = relu((Ahat x) @ W1 + b1)
    hipLaunchKernelGGL(k_agg_gemm1, dim3(512), dim3(256), 0, stream,
                       xh, rowstart, ssrc, dinv, b1, W1t, h1h, N, nchunks);
    // layer 2: hsh = (half)(dinv * (h1h @ W2)); h2h = (half) relu(dinv*(agg hsh) + b2)
    hipLaunchKernelGGL((k_gemm_mfma<256, 0>), dim3(512), dim3(256), 0, stream,
                       h1h, W2t, dinv, (const float*)nullptr, hsh, N, nchunks);
    hipLaunchKernelGGL(k_aggregate, dim3((N + 3) / 4), dim3(256), 0, stream,
                       (const __half*)hsh, rowstart, ssrc, dinv, b2, h2h, N);
    // fused pool + head
    hipLaunchKernelGGL(k_poolhead, dim3(G), dim3(256), 0, stream,
                       h2h, gstart, Wl, bl, out, G);
}

// Round 10
// 422.152 us; speedup vs baseline: 1.0546x; 1.0546x over previous
//
#include <hip/hip_runtime.h>
#include <hip/hip_fp16.h>
#include <math.h>

typedef _Float16 f16x8 __attribute__((ext_vector_type(8)));
typedef float f32x4 __attribute__((ext_vector_type(4)));

// ---------------- graph preprocessing ----------------

// counting pass; atomicAdd's return value IS the edge's rank within its dst bucket
__global__ void k_edge_count(const int* __restrict__ dst, int* __restrict__ ecnt,
                             int* __restrict__ rank, int E) {
    int j = (blockIdx.x * 256 + threadIdx.x) * 2;
    if (j + 1 < E) {
        int2 d = *(const int2*)(dst + j);
        int r0 = atomicAdd(&ecnt[d.x], 1);
        int r1 = atomicAdd(&ecnt[d.y], 1);
        *(int2*)(rank + j) = make_int2(r0, r1);
    } else if (j < E) {
        rank[j] = atomicAdd(&ecnt[dst[j]], 1);
    }
}

__global__ void k_scanA(const int* __restrict__ ecnt, int* __restrict__ bsum, int N) {
    int t = threadIdx.x;
    int base = blockIdx.x * 1024;
    int s = 0;
#pragma unroll
    for (int j = 0; j < 4; ++j) {
        int i = base + j * 256 + t;
        if (i < N) s += ecnt[i];
    }
#pragma unroll
    for (int off = 32; off > 0; off >>= 1) s += __shfl_down(s, off, 64);
    __shared__ int wsum[4];
    if ((t & 63) == 0) wsum[t >> 6] = s;
    __syncthreads();
    if (t == 0) bsum[blockIdx.x] = wsum[0] + wsum[1] + wsum[2] + wsum[3];
}

__global__ void k_scanB(const int* __restrict__ bsum, int* __restrict__ boff, int NB,
                        int* __restrict__ rowstart, int N, int E) {
    __shared__ int sh[256];
    int t = threadIdx.x;
    int v = (t < NB) ? bsum[t] : 0;
    sh[t] = v;
    __syncthreads();
    for (int off = 1; off < 256; off <<= 1) {
        int u = (t >= off) ? sh[t - off] : 0;
        __syncthreads();
        sh[t] += u;
        __syncthreads();
    }
    if (t < NB) boff[t] = sh[t] - v;  // exclusive
    if (t == 0) rowstart[N] = E;
}

__global__ void k_scanC(const int* __restrict__ ecnt, const int* __restrict__ boff,
                        int* __restrict__ rowstart, float* __restrict__ dinv, int N) {
    int t = threadIdx.x;
    int base = blockIdx.x * 1024 + t * 4;
    int e[4];
    int s = 0;
#pragma unroll
    for (int j = 0; j < 4; ++j) {
        int i = base + j;
        e[j] = (i < N) ? ecnt[i] : 0;
        s += e[j];
    }
    __shared__ int sh[256];
    sh[t] = s;
    __syncthreads();
    for (int off = 1; off < 256; off <<= 1) {
        int u = (t >= off) ? sh[t - off] : 0;
        __syncthreads();
        sh[t] += u;
        __syncthreads();
    }
    int off0 = boff[blockIdx.x] + sh[t] - s;
    int run = 0;
#pragma unroll
    for (int j = 0; j < 4; ++j) {
        int i = base + j;
        if (i < N) {
            rowstart[i] = off0 + run;
            dinv[i] = rsqrtf((float)(e[j] + 1));  // +1 self loop
        }
        run += e[j];
    }
}

// dst-range-classed atomic-free scatter.
// Class c = blockIdx.x & 7 (round-robin -> same XCD under the dispatch heuristic)
// handles only dst in [c*lo_div, (c+1)*lo_div): every 64B line of ssrc is written
// by ONE class -> single-L2 ownership -> write-combining instead of cross-XCD RMW.
// Streams (src/dst/rank) are re-read 8x, but sequentially (LLC-served).
__global__ __launch_bounds__(256) void k_scatter8(
    const int* __restrict__ src, const int* __restrict__ dst,
    const int* __restrict__ rowstart, const int* __restrict__ rank,
    int* __restrict__ ssrc, int E, int lo_div) {
    int cls = blockIdx.x & 7;
    int blk = blockIdx.x >> 3;
    int nblk = gridDim.x >> 3;
    int lo = cls * lo_div, hi = lo + lo_div;
    int nchunk = (E + 1023) / 1024;
    for (int ch = blk; ch < nchunk; ch += nblk) {
        int j = ch * 1024 + threadIdx.x * 4;
        if (j + 3 < E) {
            int4 d = *(const int4*)(dst + j);
            int4 s = *(const int4*)(src + j);
            int4 r = *(const int4*)(rank + j);
            if (d.x >= lo && d.x < hi) ssrc[rowstart[d.x] + r.x] = s.x;
            if (d.y >= lo && d.y < hi) ssrc[rowstart[d.y] + r.y] = s.y;
            if (d.z >= lo && d.z < hi) ssrc[rowstart[d.z] + r.z] = s.z;
            if (d.w >= lo && d.w < hi) ssrc[rowstart[d.w] + r.w] = s.w;
        } else {
            for (; j < E; ++j) {
                int dv = dst[j];
                if (dv >= lo && dv < hi) ssrc[rowstart[dv] + rank[j]] = src[j];
            }
        }
    }
}

// ---------------- fused prologue: ecnt init + gstarts + x cast + W transpose ----------------

__global__ __launch_bounds__(256) void k_misc(
    const float* __restrict__ x, __half* __restrict__ xh,
    const float* __restrict__ W1, const float* __restrict__ W2,
    _Float16* __restrict__ W1t, _Float16* __restrict__ W2t,
    const int* __restrict__ batch, int* __restrict__ gstart,
    int* __restrict__ ecnt, int N, int G, int n4) {
    int i = blockIdx.x * 256 + threadIdx.x;
    if (i < n4) {  // f32 -> f16 cast, 4 elems/thread
        float4 v = *(const float4*)(x + (size_t)i * 4);
        union { __half2 h[2]; float2 f; } u;
        u.h[0] = __floats2half2_rn(v.x, v.y);
        u.h[1] = __floats2half2_rn(v.z, v.w);
        *(float2*)(xh + (size_t)i * 4) = u.f;
    }
    if (i < N) {
        ecnt[i] = 0;
        int bi = batch[i];
        int bp = (i == 0) ? -1 : batch[i - 1];
        for (int g = bp + 1; g <= bi; ++g) gstart[g] = i;
        if (i == N - 1) {
            for (int g = bi + 1; g <= G; ++g) gstart[g] = N;
        }
    }
    if (i < 128 * 256) {
        int c = i >> 7, k = i & 127;
        W1t[i] = (_Float16)W1[k * 256 + c];
    } else if (i < 128 * 256 + 256 * 256) {
        int j = i - 128 * 256;
        int c = j >> 8, k = j & 255;
        W2t[j] = (_Float16)W2[k * 256 + c];
    }
}

// ---------------- layer-1 input aggregation (full-occupancy, R8-proven) ----------------
// xa_h[v] = (half) dinv[v]*(dinv[v]*xh[v] + sum dinv[u]*xh[u]); 128 dims, fp16 reads
// quarter-wave (16 lanes) per node, f16x8 (16B) per lane

__global__ __launch_bounds__(256) void k_agg_in(
    const _Float16* __restrict__ xh,
    const int* __restrict__ rowstart, const int* __restrict__ ssrc,
    const float* __restrict__ dinv, _Float16* __restrict__ xa_h, int N) {
    int qw = threadIdx.x >> 4;
    int l = threadIdx.x & 15;
    int v = blockIdx.x * 16 + qw;
    if (v >= N) return;
    float dv = dinv[v];
    float acc[8];
    {
        f16x8 s = *(const f16x8*)(xh + (size_t)v * 128 + l * 8);
#pragma unroll
        for (int j = 0; j < 8; ++j) acc[j] = (float)s[j] * dv;
    }
    int e = rowstart[v], e1 = rowstart[v + 1];
    for (; e + 4 <= e1; e += 4) {
        int u0 = ssrc[e], u1 = ssrc[e + 1], u2 = ssrc[e + 2], u3 = ssrc[e + 3];
        float d0 = dinv[u0], d1 = dinv[u1], d2 = dinv[u2], d3 = dinv[u3];
        f16x8 m0 = *(const f16x8*)(xh + (size_t)u0 * 128 + l * 8);
        f16x8 m1 = *(const f16x8*)(xh + (size_t)u1 * 128 + l * 8);
        f16x8 m2 = *(const f16x8*)(xh + (size_t)u2 * 128 + l * 8);
        f16x8 m3 = *(const f16x8*)(xh + (size_t)u3 * 128 + l * 8);
#pragma unroll
        for (int j = 0; j < 8; ++j) {
            acc[j] = fmaf((float)m0[j], d0, acc[j]);
            acc[j] = fmaf((float)m1[j], d1, acc[j]);
            acc[j] = fmaf((float)m2[j], d2, acc[j]);
            acc[j] = fmaf((float)m3[j], d3, acc[j]);
        }
    }
    for (; e < e1; ++e) {
        int u = ssrc[e];
        float d = dinv[u];
        f16x8 m = *(const f16x8*)(xh + (size_t)u * 128 + l * 8);
#pragma unroll
        for (int j = 0; j < 8; ++j) acc[j] = fmaf((float)m[j], d, acc[j]);
    }
    f16x8 o;
#pragma unroll
    for (int j = 0; j < 8; ++j) o[j] = (_Float16)(acc[j] * dv);
    *(f16x8*)(xa_h + (size_t)v * 128 + l * 8) = o;
}

// ---------------- MFMA fp16 GEMM (proven) ----------------
// EPI 0: Ch = (half)(dinv[r] * acc)      EPI 1: Ch = (half)relu(acc + bias[c])

template<int K, int EPI>
__global__ __launch_bounds__(256, 2) void k_gemm_mfma(
    const _Float16* __restrict__ Ah, const _Float16* __restrict__ Wt,
    const float* __restrict__ dinv, const float* __restrict__ bias,
    _Float16* __restrict__ Ch, int Nrows, int nchunks) {
    constexpr int KS = K / 32;
    constexpr int RB = 2 * K;
    constexpr int NLD = 64 * RB / 4096;
    __shared__ _Float16 As[64 * K];

    int tid = threadIdx.x;
    int l = tid & 63;
    int wv = tid >> 6;

    int bc = wv * 64 + (l & 15);
    int bk = (l >> 4) * 8;
    f16x8 breg[4][KS];
#pragma unroll
    for (int ct = 0; ct < 4; ++ct)
#pragma unroll
        for (int ks = 0; ks < KS; ++ks)
            breg[ct][ks] = *(const f16x8*)(Wt + (size_t)(bc + ct * 16) * K + ks * 32 + bk);
    float bb[4];
    if (EPI == 1) {
#pragma unroll
        for (int ct = 0; ct < 4; ++ct) bb[ct] = bias[bc + ct * 16];
    }

    for (int ch = blockIdx.x; ch < nchunks; ch += gridDim.x) {
        int r0 = ch * 64;
#pragma unroll
        for (int i = 0; i < NLD; ++i) {
            int logical = i * 4096 + tid * 16;
            int row = logical / RB;
            int colb = (logical & (RB - 1)) ^ ((row & 7) << 4);
            int grow = r0 + row;
            grow = grow < Nrows ? grow : Nrows - 1;
            const char* src = (const char*)Ah + (size_t)grow * RB + colb;
            char* dst = (char*)As + i * 4096 + wv * 1024;
            __builtin_amdgcn_global_load_lds(
                (const __attribute__((address_space(1))) void*)src,
                (__attribute__((address_space(3))) void*)dst, 16, 0, 0);
        }
        __syncthreads();

#pragma unroll
        for (int rb = 0; rb < 4; ++rb) {
            f32x4 acc[4];
#pragma unroll
            for (int ct = 0; ct < 4; ++ct) acc[ct] = (f32x4){0.f, 0.f, 0.f, 0.f};
            int row = rb * 16 + (l & 15);
#pragma unroll
            for (int ks = 0; ks < KS; ++ks) {
                int lb = (row * RB + ks * 64 + (l >> 4) * 16) ^ ((l & 7) << 4);
                f16x8 a = *(const f16x8*)((const char*)As + lb);
#pragma unroll
                for (int ct = 0; ct < 4; ++ct)
                    acc[ct] = __builtin_amdgcn_mfma_f32_16x16x32_f16(a, breg[ct][ks], acc[ct], 0, 0, 0);
            }
            int rbase = r0 + rb * 16 + (l >> 4) * 4;
#pragma unroll
            for (int j = 0; j < 4; ++j) {
                int r = rbase + j;
                if (r < Nrows) {
                    if (EPI == 0) {
                        float sc = dinv[r];
#pragma unroll
                        for (int ct = 0; ct < 4; ++ct)
                            Ch[(size_t)r * 256 + bc + ct * 16] = (_Float16)(acc[ct][j] * sc);
                    } else {
#pragma unroll
                        for (int ct = 0; ct < 4; ++ct)
                            Ch[(size_t)r * 256 + bc + ct * 16] =
                                (_Float16)fmaxf(acc[ct][j] + bb[ct], 0.f);
                    }
                }
            }
        }
        __syncthreads();
    }
}

// ---------------- layer-2 aggregation (proven shape, fp16 in AND out) ----------------

__device__ __forceinline__ void acc_h4s(float4& acc, float2 raw) {
    union { float2 f; __half2 h[2]; } u;
    u.f = raw;
    float2 p0 = __half22float2(u.h[0]);
    float2 p1 = __half22float2(u.h[1]);
    acc.x += p0.x; acc.y += p0.y; acc.z += p1.x; acc.w += p1.y;
}

__global__ __launch_bounds__(256) void k_aggregate(
    const __half* __restrict__ hsh, const int* __restrict__ rowstart,
    const int* __restrict__ ssrc, const float* __restrict__ dinv,
    const float* __restrict__ bias, __half* __restrict__ h2h, int N) {
    int w = threadIdx.x >> 6;
    int l = threadIdx.x & 63;
    int v = blockIdx.x * 4 + w;
    if (v >= N) return;
    float4 acc = make_float4(0.f, 0.f, 0.f, 0.f);
    acc_h4s(acc, *(const float2*)(hsh + (size_t)v * 256 + l * 4));  // self loop
    int e = rowstart[v], e1 = rowstart[v + 1];
    for (; e + 4 <= e1; e += 4) {
        int u0 = ssrc[e], u1 = ssrc[e + 1], u2 = ssrc[e + 2], u3 = ssrc[e + 3];
        float2 m0 = *(const float2*)(hsh + (size_t)u0 * 256 + l * 4);
        float2 m1 = *(const float2*)(hsh + (size_t)u1 * 256 + l * 4);
        float2 m2 = *(const float2*)(hsh + (size_t)u2 * 256 + l * 4);
        float2 m3 = *(const float2*)(hsh + (size_t)u3 * 256 + l * 4);
        acc_h4s(acc, m0);
        acc_h4s(acc, m1);
        acc_h4s(acc, m2);
        acc_h4s(acc, m3);
    }
    for (; e < e1; ++e) {
        int u = ssrc[e];
        acc_h4s(acc, *(const float2*)(hsh + (size_t)u * 256 + l * 4));
    }
    float d = dinv[v];
    float4 b = *(const float4*)(bias + l * 4);
    union { __half2 h[2]; float2 f; } uo;
    uo.h[0] = __floats2half2_rn(fmaxf(fmaf(acc.x, d, b.x), 0.f),
                                fmaxf(fmaf(acc.y, d, b.y), 0.f));
    uo.h[1] = __floats2half2_rn(fmaxf(fmaf(acc.z, d, b.z), 0.f),
                                fmaxf(fmaf(acc.w, d, b.w), 0.f));
    *(float2*)(h2h + (size_t)v * 256 + l * 4) = uo.f;
}

// ---------------- fused pool + head ----------------

__global__ __launch_bounds__(256) void k_poolhead(
    const __half* __restrict__ h2h, const int* __restrict__ gstart,
    const float* __restrict__ Wl, const float* __restrict__ bl,
    float* __restrict__ out, int G) {
    int g = blockIdx.x;
    int t = threadIdx.x;
    int i0 = gstart[g], i1 = gstart[g + 1];
    float s = 0.f;
    for (int i = i0; i < i1; ++i) s += __half2float(h2h[(size_t)i * 256 + t]);
    float pooled = s / fmaxf((float)(i1 - i0), 1.f);
    float v = pooled * Wl[t];
#pragma unroll
    for (int off = 32; off > 0; off >>= 1) v += __shfl_down(v, off, 64);
    __shared__ float red[4];
    if ((t & 63) == 0) red[t >> 6] = v;
    __syncthreads();
    if (t == 0) out[g] = red[0] + red[1] + red[2] + red[3] + bl[0];
}

// ---------------- launch ----------------

extern "C" void kernel_launch(void* const* d_in, const int* in_sizes, int n_in,
                              void* d_out, int out_size, void* d_ws, size_t ws_size,
                              hipStream_t stream) {
    const float* x  = (const float*)d_in[0];
    const int* ei   = (const int*)d_in[1];
    const int* batch= (const int*)d_in[2];
    const float* W1 = (const float*)d_in[3];
    const float* b1 = (const float*)d_in[4];
    const float* W2 = (const float*)d_in[5];
    const float* b2 = (const float*)d_in[6];
    const float* Wl = (const float*)d_in[7];
    const float* bl = (const float*)d_in[8];
    float* out = (float*)d_out;

    const int N = in_sizes[2];
    const int E = in_sizes[1] / 2;
    const int G = out_size;

    char* wsp = (char*)d_ws;
    size_t off = 0;
    auto carve = [&](size_t bytes) -> void* {
        void* p = wsp + off;
        off = (off + bytes + 255) & ~(size_t)255;
        return p;
    };
    float* bufA    = (float*)carve((size_t)N * 256 * 4);
    float* bufB    = (float*)carve((size_t)N * 256 * 4);
    float* dinv    = (float*)carve((size_t)N * 4);
    int* ecnt      = (int*)carve((size_t)N * 4);
    int* rowstart  = (int*)carve((size_t)(N + 1) * 4);
    int* rank      = (int*)carve((size_t)E * 4);
    int* ssrc      = (int*)carve((size_t)E * 4);
    const int NB = (N + 1023) / 1024;
    int* bsum      = (int*)carve((size_t)NB * 4);
    int* boff      = (int*)carve((size_t)NB * 4);
    int* gstart    = (int*)carve((size_t)(G + 1) * 4);
    _Float16* W1t  = (_Float16*)carve((size_t)256 * 128 * 2);
    _Float16* W2t  = (_Float16*)carve((size_t)256 * 256 * 2);
    (void)ws_size;

    // aliases (liveness-checked, sequential stream):
    // bufA: xh [0,25.6MB) | xa_h [25.6,51.2) | h1h [51.2,102.4)
    // bufB: hsh [0,51.2)  | h2h [51.2,102.4)
    _Float16* xh   = (_Float16*)bufA;
    _Float16* xa_h = (_Float16*)((char*)bufA + (size_t)N * 128 * 2);
    _Float16* h1h  = (_Float16*)((char*)bufA + (size_t)N * 128 * 4);
    _Float16* hsh  = (_Float16*)bufB;
    __half*   h2h  = (__half*)((char*)bufB + (size_t)N * 256 * 2);

    const int* esrc = ei;
    const int* edst = ei + E;

    int nchunks = (N + 63) / 64;
    int n4 = N * 32;  // float4 count for the cast
    int lo_div = (N + 7) / 8;

    hipLaunchKernelGGL(k_misc, dim3((n4 + 255) / 256), dim3(256), 0, stream,
                       x, (__half*)xh, W1, W2, W1t, W2t, batch, gstart, ecnt, N, G, n4);
    hipLaunchKernelGGL(k_edge_count, dim3((E / 2 + 255) / 256), dim3(256), 0, stream,
                       edst, ecnt, rank, E);
    hipLaunchKernelGGL(k_scanA, dim3(NB), dim3(256), 0, stream, ecnt, bsum, N);
    hipLaunchKernelGGL(k_scanB, dim3(1), dim3(256), 0, stream, bsum, boff, NB, rowstart, N, E);
    hipLaunchKernelGGL(k_scanC, dim3(NB), dim3(256), 0, stream, ecnt, boff, rowstart, dinv, N);
    hipLaunchKernelGGL(k_scatter8, dim3(2048), dim3(256), 0, stream,
                       esrc, edst, rowstart, rank, ssrc, E, lo_div);

    // layer 1: xa_h = (half) Ahat x ; h1h = (half) relu(xa_h @ W1 + b1)
    hipLaunchKernelGGL(k_agg_in, dim3((N + 15) / 16), dim3(256), 0, stream,
                       xh, rowstart, ssrc, dinv, xa_h, N);
    hipLaunchKernelGGL((k_gemm_mfma<128, 1>), dim3(512), dim3(256), 0, stream,
                       xa_h, W1t, (const float*)nullptr, b1, h1h, N, nchunks);
    // layer 2: hsh = (half)(dinv * (h1h @ W2)); h2h = (half) relu(dinv*(agg hsh) + b2)
    hipLaunchKernelGGL((k_gemm_mfma<256, 0>), dim3(512), dim3(256), 0, stream,
                       h1h, W2t, dinv, (const float*)nullptr, hsh, N, nchunks);
    hipLaunchKernelGGL(k_aggregate, dim3((N + 3) / 4), dim3(256), 0, stream,
                       (const __half*)hsh, rowstart, ssrc, dinv, b2, h2h, N);
    // fused pool + head
    hipLaunchKernelGGL(k_poolhead, dim3(G), dim3(256), 0, stream,
                       h2h, gstart, Wl, bl, out, G);
}